// Round 15
// baseline (407.878 us; speedup 1.0000x reference)
//
#include <hip/hip_runtime.h>
#include <hip/hip_bf16.h>
#include <math.h>

#define N_NODES 100000
#define N_EDGES 1600000
#define TOT_E   (N_EDGES + N_NODES)
#define NBG     ((N_NODES + 127) / 128)   // 782 gemm blocks
#define NBC     ((TOT_E + 255) / 256)     // 6641 count/fill blocks
#define NBA     800                       // alpha1 blocks, 125 nodes each

__device__ __forceinline__ float lrelu(float v){ return v > 0.f ? v : 0.2f * v; }
__device__ __forceinline__ float elu_(float v){ return v > 0.f ? v : expm1f(v); }
__device__ __forceinline__ ushort f2bf(float f){
  unsigned u = __float_as_uint(f);
  u = (u + 0x7FFFu + ((u >> 16) & 1u)) >> 16;   // RNE
  return (ushort)u;
}
__device__ __forceinline__ float bf2f(ushort u){
  return __uint_as_float(((unsigned)u) << 16);
}
__device__ __forceinline__ float bflo(unsigned p){ return __uint_as_float(p << 16); }
__device__ __forceinline__ float bfhi(unsigned p){ return __uint_as_float(p & 0xffff0000u); }

// ---------- fused front: alpha1-from-x | edge count | prep2 ----------
// alpha1 by linearity: as1[n] = x[n] . (W1 @ a_src1_head), per head (fp32 reassoc only)
__global__ __launch_bounds__(256) void k_front(const float* __restrict__ x, const float* __restrict__ W1,
                                               const float* __restrict__ a_src1, const float* __restrict__ a_dst1,
                                               const int* __restrict__ ei, int* __restrict__ cnt,
                                               const float* __restrict__ W2, const float* __restrict__ a_src2,
                                               const float* __restrict__ a_dst2, float* __restrict__ vs2,
                                               float* __restrict__ vd2,
                                               float* __restrict__ as1, float* __restrict__ ad1){
  __shared__ float vls[2][128], vld[2][128];
  int bid = blockIdx.x;
  if (bid < NBA){
    // per-block projection vectors: vls[h][k] = sum_c W1[k][h*64+c]*a_src1[h][c]
    for (int item = threadIdx.x; item < 512; item += 256){
      int vec = item >> 7;          // 0: s h0, 1: s h1, 2: d h0, 3: d h1
      int k   = item & 127;
      int hd  = vec & 1;
      bool isS = vec < 2;
      const float* av = (isS ? a_src1 : a_dst1) + hd * 64;
      const float* wr = W1 + k * 128 + hd * 64;
      float acc = 0.f;
      #pragma unroll 8
      for (int c = 0; c < 64; ++c) acc = fmaf(wr[c], av[c], acc);
      if (isS) vls[hd][k] = acc; else vld[hd][k] = acc;
    }
    __syncthreads();
    int wv = threadIdx.x >> 6;
    int lane = threadIdx.x & 63;
    int nend = bid * 125 + 125;     // 800*125 = 100000 exact
    for (int n = bid * 125 + wv; n < nend; n += 4){
      float2 xv = *(const float2*)(x + (size_t)n * 128 + lane * 2);
      float s0 = fmaf(xv.x, vls[0][lane*2], xv.y * vls[0][lane*2+1]);
      float s1 = fmaf(xv.x, vls[1][lane*2], xv.y * vls[1][lane*2+1]);
      float d0 = fmaf(xv.x, vld[0][lane*2], xv.y * vld[0][lane*2+1]);
      float d1 = fmaf(xv.x, vld[1][lane*2], xv.y * vld[1][lane*2+1]);
      #pragma unroll
      for (int m = 32; m; m >>= 1){
        s0 += __shfl_xor(s0, m); s1 += __shfl_xor(s1, m);
        d0 += __shfl_xor(d0, m); d1 += __shfl_xor(d1, m);
      }
      if (lane == 0){
        as1[2*n] = s0; as1[2*n+1] = s1;
        ad1[2*n] = d0; ad1[2*n+1] = d1;
      }
    }
  } else if (bid < NBA + NBC){
    int i = (bid - NBA) * 256 + threadIdx.x;
    if (i < TOT_E){
      int d = (i < N_EDGES) ? ei[N_EDGES + i] : (i - N_EDGES);
      atomicAdd(&cnt[d], 1);
    }
  } else {
    int k = threadIdx.x;
    if (k < 128){
      float s = 0.f, d = 0.f;
      for (int c = 0; c < 64; ++c){
        float w = W2[k * 64 + c];
        s = fmaf(w, a_src2[c], s);
        d = fmaf(w, a_dst2[c], d);
      }
      vs2[k] = s; vd2[k] = d;
    }
  }
}

// ---------------- scans ----------------
__global__ __launch_bounds__(1024) void k_scan1(const int* __restrict__ cnt, int* __restrict__ off,
                                                int* __restrict__ bs){
  __shared__ int s[1024];
  int t = threadIdx.x;
  int i = blockIdx.x * 1024 + t;
  int v = (i < N_NODES) ? cnt[i] : 0;
  s[t] = v;
  __syncthreads();
  for (int o = 1; o < 1024; o <<= 1){
    int tmp = 0;
    if (t >= o) tmp = s[t - o];
    __syncthreads();
    if (t >= o) s[t] += tmp;
    __syncthreads();
  }
  if (i < N_NODES) off[i] = s[t] - v;
  if (t == 1023) bs[blockIdx.x] = s[1023];
}

__global__ __launch_bounds__(128) void k_scan2(int* __restrict__ bs, int* __restrict__ off, int nb){
  __shared__ int s[128];
  int t = threadIdx.x;
  int v = (t < nb) ? bs[t] : 0;
  s[t] = v;
  __syncthreads();
  #pragma unroll
  for (int o = 1; o < 128; o <<= 1){
    int tmp = 0;
    if (t >= o) tmp = s[t - o];
    __syncthreads();
    if (t >= o) s[t] += tmp;
    __syncthreads();
  }
  if (t < nb) bs[t] = s[t] - v;
  if (t == nb - 1) off[N_NODES] = s[t];
}

__global__ __launch_bounds__(1024) void k_scan3(int* __restrict__ off, int* __restrict__ cur,
                                                const int* __restrict__ bs){
  int i = blockIdx.x * 1024 + threadIdx.x;
  if (i < N_NODES){
    int v = off[i] + bs[blockIdx.x];
    off[i] = v;
    cur[i] = v;
  }
}

// ---------- fused back: layer-1 GEMM (h only) | fill_w (independent) ----------
__global__ __launch_bounds__(256) void k_back(const float* __restrict__ x, const float* __restrict__ W,
                                              ushort* __restrict__ h, int n,
                                              const int* __restrict__ ei, int* __restrict__ cur,
                                              uint4* __restrict__ csr4,
                                              const float* __restrict__ as1, const float* __restrict__ ad1){
  __shared__ float sx[128][36];
  __shared__ float sw[32][132];

  if (blockIdx.x >= NBG){
    // ---- fill_w path (needs as1/ad1 from k_front + cur from scans) ----
    int i = (blockIdx.x - NBG) * 256 + threadIdx.x;
    if (i < TOT_E){
      int s, d;
      if (i < N_EDGES){ s = ei[i]; d = ei[N_EDGES + i]; }
      else            { s = d = i - N_EDGES; }
      int p = atomicAdd(&cur[d], 1);
      float2 a  = *(const float2*)(as1 + 2u * (unsigned)s);
      float2 ad = *(const float2*)(ad1 + 2u * (unsigned)d);
      uint4 v;
      v.x = (unsigned)s;
      v.y = __float_as_uint(__expf(lrelu(a.x + ad.x)));
      v.z = __float_as_uint(__expf(lrelu(a.y + ad.y)));
      v.w = (unsigned)d;
      csr4[p] = v;
    }
    return;
  }

  // ---- GEMM path (h only; alpha1 moved to k_front) ----
  const int tid  = threadIdx.x;
  const int cg   = tid & 7;
  const int slot = tid >> 3;
  const int rbase = blockIdx.x * 128;
  const int r0   = rbase + slot * 4;
  const int col0 = cg * 16;

  float acc[4][16] = {};

  for (int kc = 0; kc < 4; ++kc){
    __syncthreads();
    #pragma unroll
    for (int i = 0; i < 4; ++i){
      int f   = tid + 256 * i;
      int row = f >> 3;
      int c4  = f & 7;
      int gr  = rbase + row; if (gr > n - 1) gr = n - 1;
      float4 v = *(const float4*)(x + (size_t)gr * 128 + kc * 32 + c4 * 4);
      *(float4*)(&sx[row][c4 * 4]) = v;
    }
    #pragma unroll
    for (int i = 0; i < 4; ++i){
      int f  = tid + 256 * i;
      int k  = f >> 5;
      int c4 = f & 31;
      float4 v = *(const float4*)(W + (size_t)(kc * 32 + k) * 128 + c4 * 4);
      *(float4*)(&sw[k][c4 * 4]) = v;
    }
    __syncthreads();

    #pragma unroll 8
    for (int j = 0; j < 32; ++j){
      float4 w0 = *(const float4*)(&sw[j][col0]);
      float4 w1 = *(const float4*)(&sw[j][col0 + 4]);
      float4 w2 = *(const float4*)(&sw[j][col0 + 8]);
      float4 w3 = *(const float4*)(&sw[j][col0 + 12]);
      #pragma unroll
      for (int i = 0; i < 4; ++i){
        float xv = sx[slot * 4 + i][j];
        acc[i][0]  = fmaf(xv, w0.x, acc[i][0]);  acc[i][1]  = fmaf(xv, w0.y, acc[i][1]);
        acc[i][2]  = fmaf(xv, w0.z, acc[i][2]);  acc[i][3]  = fmaf(xv, w0.w, acc[i][3]);
        acc[i][4]  = fmaf(xv, w1.x, acc[i][4]);  acc[i][5]  = fmaf(xv, w1.y, acc[i][5]);
        acc[i][6]  = fmaf(xv, w1.z, acc[i][6]);  acc[i][7]  = fmaf(xv, w1.w, acc[i][7]);
        acc[i][8]  = fmaf(xv, w2.x, acc[i][8]);  acc[i][9]  = fmaf(xv, w2.y, acc[i][9]);
        acc[i][10] = fmaf(xv, w2.z, acc[i][10]); acc[i][11] = fmaf(xv, w2.w, acc[i][11]);
        acc[i][12] = fmaf(xv, w3.x, acc[i][12]); acc[i][13] = fmaf(xv, w3.y, acc[i][13]);
        acc[i][14] = fmaf(xv, w3.z, acc[i][14]); acc[i][15] = fmaf(xv, w3.w, acc[i][15]);
      }
    }
  }

  #pragma unroll
  for (int i = 0; i < 4; ++i){
    int r = r0 + i;
    if (r < n){
      union { uint4 q[2]; ushort us[16]; } pk;
      #pragma unroll
      for (int j = 0; j < 16; ++j) pk.us[j] = f2bf(acc[i][j]);
      uint4* dst = (uint4*)(h + (size_t)r * 128 + col0);
      dst[0] = pk.q[0]; dst[1] = pk.q[1];
    }
  }
}

// layer-2 packed edge records {src, w2} (runs AFTER agg1)
__global__ __launch_bounds__(256) void k_ew2(const uint4* __restrict__ csr4,
                                             const float* __restrict__ as2, const float* __restrict__ ad2,
                                             uint2* __restrict__ ew){
  int i = blockIdx.x * 256 + threadIdx.x;
  if (i >= TOT_E) return;
  uint4 v = csr4[i];
  float w = __expf(lrelu(as2[v.x] + ad2[v.w]));
  ew[i] = make_uint2(v.x, __float_as_uint(w));
}

// ------- layer-1 agg: FULL-WAVE, 1 row/instr, scalar edge records -------
__global__ __launch_bounds__(256) void k_agg1(const int* __restrict__ off, const uint4* __restrict__ csr4,
                                              const ushort* __restrict__ h,
                                              const float* __restrict__ b,
                                              const float* __restrict__ vs2, const float* __restrict__ vd2,
                                              const float* __restrict__ W2,
                                              ushort* __restrict__ z, float* __restrict__ as2,
                                              float* __restrict__ ad2){
  __shared__ float yly[4][128];          // per-wave y row (wave-private)
  int wid  = threadIdx.x >> 6;
  int node = blockIdx.x * 4 + wid;
  int lane = threadIdx.x & 63;
  int head = lane >> 5;
  int c0   = lane * 2;
  int s0 = off[node], e0 = off[node + 1];

  float acc0 = 0.f, acc1 = 0.f, den = 0.f;
  int k = s0;
  for (; k + 7 < e0; k += 8){
    int ku = __builtin_amdgcn_readfirstlane(k);
    uint4 eA = csr4[ku],     eB = csr4[ku + 1], eC = csr4[ku + 2], eD = csr4[ku + 3];
    uint4 eE = csr4[ku + 4], eF = csr4[ku + 5], eG = csr4[ku + 6], eH = csr4[ku + 7];
    unsigned hA = *(const unsigned*)(h + ((size_t)eA.x << 7) + c0);
    unsigned hB = *(const unsigned*)(h + ((size_t)eB.x << 7) + c0);
    unsigned hC = *(const unsigned*)(h + ((size_t)eC.x << 7) + c0);
    unsigned hD = *(const unsigned*)(h + ((size_t)eD.x << 7) + c0);
    unsigned hE = *(const unsigned*)(h + ((size_t)eE.x << 7) + c0);
    unsigned hF = *(const unsigned*)(h + ((size_t)eF.x << 7) + c0);
    unsigned hG = *(const unsigned*)(h + ((size_t)eG.x << 7) + c0);
    unsigned hH = *(const unsigned*)(h + ((size_t)eH.x << 7) + c0);
    float wA = __uint_as_float(head ? eA.z : eA.y);
    float wB = __uint_as_float(head ? eB.z : eB.y);
    float wC = __uint_as_float(head ? eC.z : eC.y);
    float wD = __uint_as_float(head ? eD.z : eD.y);
    float wE = __uint_as_float(head ? eE.z : eE.y);
    float wF = __uint_as_float(head ? eF.z : eF.y);
    float wG = __uint_as_float(head ? eG.z : eG.y);
    float wH = __uint_as_float(head ? eH.z : eH.y);
    den += ((wA + wB) + (wC + wD)) + ((wE + wF) + (wG + wH));
    acc0 = fmaf(wA, bflo(hA), acc0); acc1 = fmaf(wA, bfhi(hA), acc1);
    acc0 = fmaf(wB, bflo(hB), acc0); acc1 = fmaf(wB, bfhi(hB), acc1);
    acc0 = fmaf(wC, bflo(hC), acc0); acc1 = fmaf(wC, bfhi(hC), acc1);
    acc0 = fmaf(wD, bflo(hD), acc0); acc1 = fmaf(wD, bfhi(hD), acc1);
    acc0 = fmaf(wE, bflo(hE), acc0); acc1 = fmaf(wE, bfhi(hE), acc1);
    acc0 = fmaf(wF, bflo(hF), acc0); acc1 = fmaf(wF, bfhi(hF), acc1);
    acc0 = fmaf(wG, bflo(hG), acc0); acc1 = fmaf(wG, bfhi(hG), acc1);
    acc0 = fmaf(wH, bflo(hH), acc0); acc1 = fmaf(wH, bfhi(hH), acc1);
  }
  if (k + 3 < e0){
    int ku = __builtin_amdgcn_readfirstlane(k);
    uint4 eA = csr4[ku],     eB = csr4[ku + 1], eC = csr4[ku + 2], eD = csr4[ku + 3];
    unsigned hA = *(const unsigned*)(h + ((size_t)eA.x << 7) + c0);
    unsigned hB = *(const unsigned*)(h + ((size_t)eB.x << 7) + c0);
    unsigned hC = *(const unsigned*)(h + ((size_t)eC.x << 7) + c0);
    unsigned hD = *(const unsigned*)(h + ((size_t)eD.x << 7) + c0);
    float wA = __uint_as_float(head ? eA.z : eA.y);
    float wB = __uint_as_float(head ? eB.z : eB.y);
    float wC = __uint_as_float(head ? eC.z : eC.y);
    float wD = __uint_as_float(head ? eD.z : eD.y);
    den += (wA + wB) + (wC + wD);
    acc0 = fmaf(wA, bflo(hA), acc0); acc1 = fmaf(wA, bfhi(hA), acc1);
    acc0 = fmaf(wB, bflo(hB), acc0); acc1 = fmaf(wB, bfhi(hB), acc1);
    acc0 = fmaf(wC, bflo(hC), acc0); acc1 = fmaf(wC, bfhi(hC), acc1);
    acc0 = fmaf(wD, bflo(hD), acc0); acc1 = fmaf(wD, bfhi(hD), acc1);
    k += 4;
  }
  for (; k < e0; ++k){
    int ku = __builtin_amdgcn_readfirstlane(k);
    uint4 eA = csr4[ku];
    unsigned hA = *(const unsigned*)(h + ((size_t)eA.x << 7) + c0);
    float wA = __uint_as_float(head ? eA.z : eA.y);
    den += wA;
    acc0 = fmaf(wA, bflo(hA), acc0); acc1 = fmaf(wA, bfhi(hA), acc1);
  }

  float inv = 1.f / (den + 1e-16f);
  float o0 = elu_(acc0 * inv + b[c0]);
  float o1 = elu_(acc1 * inv + b[c0 + 1]);

  *(float2*)(&yly[wid][c0]) = make_float2(o0, o1);

  float s2 = fmaf(o0, vs2[c0], o1 * vs2[c0 + 1]);
  float d2 = fmaf(o0, vd2[c0], o1 * vd2[c0 + 1]);
  #pragma unroll
  for (int m = 32; m; m >>= 1){ s2 += __shfl_xor(s2, m); d2 += __shfl_xor(d2, m); }
  if (lane == 0){ as2[node] = s2; ad2[node] = d2; }

  asm volatile("s_waitcnt lgkmcnt(0)" ::: "memory");

  float zacc = 0.f;
  const float* yw = yly[wid];
  #pragma unroll 4
  for (int q = 0; q < 32; ++q){
    float4 yv = *(const float4*)(yw + 4 * q);
    const float* wr = W2 + (q * 4) * 64 + lane;
    zacc = fmaf(yv.x, wr[0],   zacc);
    zacc = fmaf(yv.y, wr[64],  zacc);
    zacc = fmaf(yv.z, wr[128], zacc);
    zacc = fmaf(yv.w, wr[192], zacc);
  }
  z[((unsigned)node << 6) + lane] = f2bf(zacc);
}

// ------- layer-2 agg: FULL-WAVE, 1 row/instr, scalar edge records -------
__global__ __launch_bounds__(256) void k_agg2(const int* __restrict__ off, const uint2* __restrict__ ew,
                                              const ushort* __restrict__ z,
                                              const float* __restrict__ b2, float* __restrict__ out){
  int node = blockIdx.x * 4 + (threadIdx.x >> 6);
  int lane = threadIdx.x & 63;
  int s0 = off[node], e0 = off[node + 1];

  float acc = 0.f, den = 0.f;
  int k = s0;
  for (; k + 7 < e0; k += 8){
    int ku = __builtin_amdgcn_readfirstlane(k);
    uint2 eA = ew[ku],     eB = ew[ku + 1], eC = ew[ku + 2], eD = ew[ku + 3];
    uint2 eE = ew[ku + 4], eF = ew[ku + 5], eG = ew[ku + 6], eH = ew[ku + 7];
    ushort zA = z[((size_t)eA.x << 6) + lane];
    ushort zB = z[((size_t)eB.x << 6) + lane];
    ushort zC = z[((size_t)eC.x << 6) + lane];
    ushort zD = z[((size_t)eD.x << 6) + lane];
    ushort zE = z[((size_t)eE.x << 6) + lane];
    ushort zF = z[((size_t)eF.x << 6) + lane];
    ushort zG = z[((size_t)eG.x << 6) + lane];
    ushort zH = z[((size_t)eH.x << 6) + lane];
    float wA = __uint_as_float(eA.y), wB = __uint_as_float(eB.y);
    float wC = __uint_as_float(eC.y), wD = __uint_as_float(eD.y);
    float wE = __uint_as_float(eE.y), wF = __uint_as_float(eF.y);
    float wG = __uint_as_float(eG.y), wH = __uint_as_float(eH.y);
    den += ((wA + wB) + (wC + wD)) + ((wE + wF) + (wG + wH));
    acc = fmaf(wA, bf2f(zA), acc); acc = fmaf(wB, bf2f(zB), acc);
    acc = fmaf(wC, bf2f(zC), acc); acc = fmaf(wD, bf2f(zD), acc);
    acc = fmaf(wE, bf2f(zE), acc); acc = fmaf(wF, bf2f(zF), acc);
    acc = fmaf(wG, bf2f(zG), acc); acc = fmaf(wH, bf2f(zH), acc);
  }
  if (k + 3 < e0){
    int ku = __builtin_amdgcn_readfirstlane(k);
    uint2 eA = ew[ku], eB = ew[ku + 1], eC = ew[ku + 2], eD = ew[ku + 3];
    ushort zA = z[((size_t)eA.x << 6) + lane];
    ushort zB = z[((size_t)eB.x << 6) + lane];
    ushort zC = z[((size_t)eC.x << 6) + lane];
    ushort zD = z[((size_t)eD.x << 6) + lane];
    float wA = __uint_as_float(eA.y), wB = __uint_as_float(eB.y);
    float wC = __uint_as_float(eC.y), wD = __uint_as_float(eD.y);
    den += (wA + wB) + (wC + wD);
    acc = fmaf(wA, bf2f(zA), acc); acc = fmaf(wB, bf2f(zB), acc);
    acc = fmaf(wC, bf2f(zC), acc); acc = fmaf(wD, bf2f(zD), acc);
    k += 4;
  }
  for (; k < e0; ++k){
    int ku = __builtin_amdgcn_readfirstlane(k);
    uint2 eA = ew[ku];
    ushort zA = z[((size_t)eA.x << 6) + lane];
    float wA = __uint_as_float(eA.y);
    den += wA;
    acc = fmaf(wA, bf2f(zA), acc);
  }

  float inv = 1.f / (den + 1e-16f);
  out[((unsigned)node << 6) + lane] = elu_(acc * inv + b2[lane]);
}

// ---------------- host ----------------
extern "C" void kernel_launch(void* const* d_in, const int* in_sizes, int n_in,
                              void* d_out, int out_size, void* d_ws, size_t ws_size,
                              hipStream_t stream){
  const float* x      = (const float*)d_in[0];
  const int*   ei     = (const int*)d_in[1];
  const float* W1     = (const float*)d_in[2];
  const float* a_src1 = (const float*)d_in[3];
  const float* a_dst1 = (const float*)d_in[4];
  const float* b1     = (const float*)d_in[5];
  const float* W2     = (const float*)d_in[6];
  const float* a_src2 = (const float*)d_in[7];
  const float* a_dst2 = (const float*)d_in[8];
  const float* b2     = (const float*)d_in[9];
  float* out = (float*)d_out;

  // workspace (~57 MB); h1 (bf16) lives in d_out until k_agg2 overwrites it
  char* ws = (char*)d_ws;
  size_t o = 0;
  auto alloc = [&](size_t bytes){ size_t r = o; o = (o + bytes + 255) & ~(size_t)255; return r; };
  int*    tmpN = (int*)(ws + alloc((size_t)N_NODES * 4));
  int*    bs   = (int*)(ws + alloc(512));
  int*    off  = (int*)(ws + alloc((size_t)(N_NODES + 1) * 4));
  uint4*  csr4 = (uint4*)(ws + alloc((size_t)TOT_E * 16));
  uint2*  ew   = (uint2*)(ws + alloc((size_t)TOT_E * 8));
  float*  as1  = (float*)(ws + alloc((size_t)N_NODES * 2 * 4));
  float*  ad1  = (float*)(ws + alloc((size_t)N_NODES * 2 * 4));
  float*  as2  = (float*)(ws + alloc((size_t)N_NODES * 4));
  float*  ad2  = (float*)(ws + alloc((size_t)N_NODES * 4));
  float*  vs2  = (float*)(ws + alloc(512));
  float*  vd2  = (float*)(ws + alloc(512));
  ushort* z    = (ushort*)(ws + alloc((size_t)N_NODES * 64 * 2));
  ushort* h1   = (ushort*)d_out;
  (void)ws_size; (void)in_sizes; (void)n_in; (void)out_size;

  const int nblk_scan  = (N_NODES + 1023) / 1024;
  const int nblk_wave4 = N_NODES / 4;

  // zero counts (k_front's count path needs it)
  hipMemsetAsync(tmpN, 0, (size_t)N_NODES * 4, stream);

  // front: alpha1-from-x | count | prep2 (all independent of the GEMM)
  k_front<<<NBA + NBC + 1, 256, 0, stream>>>(x, W1, a_src1, a_dst1, ei, tmpN,
                                             W2, a_src2, a_dst2, vs2, vd2, as1, ad1);

  // scans
  k_scan1<<<nblk_scan, 1024, 0, stream>>>(tmpN, off, bs);
  k_scan2<<<1, 128, 0, stream>>>(bs, off, nblk_scan);
  k_scan3<<<nblk_scan, 1024, 0, stream>>>(off, tmpN, bs);

  // back: gemm1 (h only) || fill_w — mutually independent, run concurrently
  k_back<<<NBG + NBC, 256, 0, stream>>>(x, W1, h1, N_NODES, ei, tmpN, csr4, as1, ad1);

  // layer-1 agg: full-wave rows, scalar edge records, fused z=y@W2 + alpha2
  k_agg1<<<nblk_wave4, 256, 0, stream>>>(off, csr4, h1, b1, vs2, vd2, W2, z, as2, ad2);

  // layer-2 packed edge weights, then full-wave agg2
  k_ew2 <<<(TOT_E + 255) / 256, 256, 0, stream>>>(csr4, as2, ad2, ew);
  k_agg2<<<nblk_wave4, 256, 0, stream>>>(off, ew, z, b2, out);
}

// Round 16
// 374.096 us; speedup vs baseline: 1.0903x; 1.0903x over previous
//
#include <hip/hip_runtime.h>
#include <hip/hip_bf16.h>
#include <math.h>

#define N_NODES 100000
#define N_EDGES 1600000
#define TOT_E   (N_EDGES + N_NODES)
#define NBG     ((N_NODES + 127) / 128)   // 782 gemm blocks
#define NBC     ((TOT_E + 255) / 256)     // 6641 count blocks

__device__ __forceinline__ float lrelu(float v){ return v > 0.f ? v : 0.2f * v; }
__device__ __forceinline__ float elu_(float v){ return v > 0.f ? v : expm1f(v); }
__device__ __forceinline__ ushort f2bf(float f){
  unsigned u = __float_as_uint(f);
  u = (u + 0x7FFFu + ((u >> 16) & 1u)) >> 16;   // RNE
  return (ushort)u;
}
__device__ __forceinline__ float bf2f(ushort u){
  return __uint_as_float(((unsigned)u) << 16);
}
__device__ __forceinline__ float bflo(unsigned p){ return __uint_as_float(p << 16); }
__device__ __forceinline__ float bfhi(unsigned p){ return __uint_as_float(p & 0xffff0000u); }

// ---------------- fused: layer-1 GEMM (+alpha1) | edge count | prep2 ----------------
__global__ __launch_bounds__(256) void k_gc(const float* __restrict__ x, const float* __restrict__ W,
                                            const float* __restrict__ a_src, const float* __restrict__ a_dst,
                                            ushort* __restrict__ h, float* __restrict__ as1,
                                            float* __restrict__ ad1,
                                            const int* __restrict__ ei, int* __restrict__ cnt,
                                            const float* __restrict__ W2, const float* __restrict__ a_src2,
                                            const float* __restrict__ a_dst2, float* __restrict__ vs,
                                            float* __restrict__ vd, int n){
  __shared__ float sx[128][36];
  __shared__ float sw[32][132];

  if (blockIdx.x >= NBG){
    if (blockIdx.x < NBG + NBC){
      // ---- count path ----
      int i = (blockIdx.x - NBG) * 256 + threadIdx.x;
      if (i < TOT_E){
        int d = (i < N_EDGES) ? ei[N_EDGES + i] : (i - N_EDGES);
        atomicAdd(&cnt[d], 1);
      }
    } else {
      // ---- prep2 path (one block) ----
      int k = threadIdx.x;
      if (k < 128){
        float s = 0.f, d = 0.f;
        for (int c = 0; c < 64; ++c){
          float w = W2[k * 64 + c];
          s = fmaf(w, a_src2[c], s);
          d = fmaf(w, a_dst2[c], d);
        }
        vs[k] = s; vd[k] = d;
      }
    }
    return;
  }

  // ---- GEMM path ----
  const int tid  = threadIdx.x;
  const int cg   = tid & 7;
  const int slot = tid >> 3;
  const int rbase = blockIdx.x * 128;
  const int r0   = rbase + slot * 4;
  const int col0 = cg * 16;

  float acc[4][16] = {};

  for (int kc = 0; kc < 4; ++kc){
    __syncthreads();
    #pragma unroll
    for (int i = 0; i < 4; ++i){
      int f   = tid + 256 * i;
      int row = f >> 3;
      int c4  = f & 7;
      int gr  = rbase + row; if (gr > n - 1) gr = n - 1;
      float4 v = *(const float4*)(x + (size_t)gr * 128 + kc * 32 + c4 * 4);
      *(float4*)(&sx[row][c4 * 4]) = v;
    }
    #pragma unroll
    for (int i = 0; i < 4; ++i){
      int f  = tid + 256 * i;
      int k  = f >> 5;
      int c4 = f & 31;
      float4 v = *(const float4*)(W + (size_t)(kc * 32 + k) * 128 + c4 * 4);
      *(float4*)(&sw[k][c4 * 4]) = v;
    }
    __syncthreads();

    #pragma unroll 8
    for (int j = 0; j < 32; ++j){
      float4 w0 = *(const float4*)(&sw[j][col0]);
      float4 w1 = *(const float4*)(&sw[j][col0 + 4]);
      float4 w2 = *(const float4*)(&sw[j][col0 + 8]);
      float4 w3 = *(const float4*)(&sw[j][col0 + 12]);
      #pragma unroll
      for (int i = 0; i < 4; ++i){
        float xv = sx[slot * 4 + i][j];
        acc[i][0]  = fmaf(xv, w0.x, acc[i][0]);  acc[i][1]  = fmaf(xv, w0.y, acc[i][1]);
        acc[i][2]  = fmaf(xv, w0.z, acc[i][2]);  acc[i][3]  = fmaf(xv, w0.w, acc[i][3]);
        acc[i][4]  = fmaf(xv, w1.x, acc[i][4]);  acc[i][5]  = fmaf(xv, w1.y, acc[i][5]);
        acc[i][6]  = fmaf(xv, w1.z, acc[i][6]);  acc[i][7]  = fmaf(xv, w1.w, acc[i][7]);
        acc[i][8]  = fmaf(xv, w2.x, acc[i][8]);  acc[i][9]  = fmaf(xv, w2.y, acc[i][9]);
        acc[i][10] = fmaf(xv, w2.z, acc[i][10]); acc[i][11] = fmaf(xv, w2.w, acc[i][11]);
        acc[i][12] = fmaf(xv, w3.x, acc[i][12]); acc[i][13] = fmaf(xv, w3.y, acc[i][13]);
        acc[i][14] = fmaf(xv, w3.z, acc[i][14]); acc[i][15] = fmaf(xv, w3.w, acc[i][15]);
      }
    }
  }

  #pragma unroll
  for (int i = 0; i < 4; ++i){
    int r = r0 + i;
    float sp = 0.f, dp = 0.f;
    #pragma unroll
    for (int j = 0; j < 16; ++j){
      sp = fmaf(acc[i][j], a_src[col0 + j], sp);
      dp = fmaf(acc[i][j], a_dst[col0 + j], dp);
    }
    float s0 = (col0 < 64) ? sp : 0.f, s1 = (col0 < 64) ? 0.f : sp;
    float d0 = (col0 < 64) ? dp : 0.f, d1 = (col0 < 64) ? 0.f : dp;
    #pragma unroll
    for (int m = 1; m <= 4; m <<= 1){
      s0 += __shfl_xor(s0, m); s1 += __shfl_xor(s1, m);
      d0 += __shfl_xor(d0, m); d1 += __shfl_xor(d1, m);
    }
    if (r < n){
      union { uint4 q[2]; ushort us[16]; } pk;
      #pragma unroll
      for (int j = 0; j < 16; ++j) pk.us[j] = f2bf(acc[i][j]);
      uint4* dst = (uint4*)(h + (size_t)r * 128 + col0);
      dst[0] = pk.q[0]; dst[1] = pk.q[1];
      if (cg == 0){
        as1[2 * r] = s0; as1[2 * r + 1] = s1;
        ad1[2 * r] = d0; ad1[2 * r + 1] = d1;
      }
    }
  }
}

// ---------------- scans ----------------
__global__ __launch_bounds__(1024) void k_scan1(const int* __restrict__ cnt, int* __restrict__ off,
                                                int* __restrict__ bs){
  __shared__ int s[1024];
  int t = threadIdx.x;
  int i = blockIdx.x * 1024 + t;
  int v = (i < N_NODES) ? cnt[i] : 0;
  s[t] = v;
  __syncthreads();
  for (int o = 1; o < 1024; o <<= 1){
    int tmp = 0;
    if (t >= o) tmp = s[t - o];
    __syncthreads();
    if (t >= o) s[t] += tmp;
    __syncthreads();
  }
  if (i < N_NODES) off[i] = s[t] - v;
  if (t == 1023) bs[blockIdx.x] = s[1023];
}

__global__ __launch_bounds__(128) void k_scan2(int* __restrict__ bs, int* __restrict__ off, int nb){
  __shared__ int s[128];
  int t = threadIdx.x;
  int v = (t < nb) ? bs[t] : 0;
  s[t] = v;
  __syncthreads();
  #pragma unroll
  for (int o = 1; o < 128; o <<= 1){
    int tmp = 0;
    if (t >= o) tmp = s[t - o];
    __syncthreads();
    if (t >= o) s[t] += tmp;
    __syncthreads();
  }
  if (t < nb) bs[t] = s[t] - v;
  if (t == nb - 1) off[N_NODES] = s[t];
}

__global__ __launch_bounds__(1024) void k_scan3(int* __restrict__ off, int* __restrict__ cur,
                                                const int* __restrict__ bs){
  int i = blockIdx.x * 1024 + threadIdx.x;
  if (i < N_NODES){
    int v = off[i] + bs[blockIdx.x];
    off[i] = v;
    cur[i] = v;
  }
}

// fill packed CSR {src, w_head0, w_head1, dst} (runs AFTER k_gc)
__global__ __launch_bounds__(256) void k_fill_w(const int* __restrict__ ei, int* __restrict__ cur,
                                                uint4* __restrict__ csr4,
                                                const float* __restrict__ as1, const float* __restrict__ ad1){
  int i = blockIdx.x * 256 + threadIdx.x;
  if (i >= TOT_E) return;
  int s, d;
  if (i < N_EDGES){ s = ei[i]; d = ei[N_EDGES + i]; }
  else            { s = d = i - N_EDGES; }
  int p = atomicAdd(&cur[d], 1);
  float2 a  = *(const float2*)(as1 + 2u * (unsigned)s);
  float2 ad = *(const float2*)(ad1 + 2u * (unsigned)d);
  uint4 v;
  v.x = (unsigned)s;
  v.y = __float_as_uint(__expf(lrelu(a.x + ad.x)));
  v.z = __float_as_uint(__expf(lrelu(a.y + ad.y)));
  v.w = (unsigned)d;
  csr4[p] = v;
}

// layer-2 packed edge records {src, w2} (runs AFTER agg1)
__global__ __launch_bounds__(256) void k_ew2(const uint4* __restrict__ csr4,
                                             const float* __restrict__ as2, const float* __restrict__ ad2,
                                             uint2* __restrict__ ew){
  int i = blockIdx.x * 256 + threadIdx.x;
  if (i >= TOT_E) return;
  uint4 v = csr4[i];
  float w = __expf(lrelu(as2[v.x] + ad2[v.w]));
  ew[i] = make_uint2(v.x, __float_as_uint(w));
}

// ------- layer-1 agg: FULL-WAVE, 1 row/instr, scalar edge records (R11) -------
__global__ __launch_bounds__(256) void k_agg1(const int* __restrict__ off, const uint4* __restrict__ csr4,
                                              const ushort* __restrict__ h,
                                              const float* __restrict__ b,
                                              const float* __restrict__ vs2, const float* __restrict__ vd2,
                                              const float* __restrict__ W2,
                                              ushort* __restrict__ z, float* __restrict__ as2,
                                              float* __restrict__ ad2){
  __shared__ float yly[4][128];          // per-wave y row (wave-private)
  int wid  = threadIdx.x >> 6;
  int node = blockIdx.x * 4 + wid;
  int lane = threadIdx.x & 63;
  int head = lane >> 5;
  int c0   = lane * 2;
  int s0 = off[node], e0 = off[node + 1];

  float acc0 = 0.f, acc1 = 0.f, den = 0.f;
  int k = s0;
  for (; k + 7 < e0; k += 8){
    int ku = __builtin_amdgcn_readfirstlane(k);
    uint4 eA = csr4[ku],     eB = csr4[ku + 1], eC = csr4[ku + 2], eD = csr4[ku + 3];
    uint4 eE = csr4[ku + 4], eF = csr4[ku + 5], eG = csr4[ku + 6], eH = csr4[ku + 7];
    unsigned hA = *(const unsigned*)(h + ((size_t)eA.x << 7) + c0);
    unsigned hB = *(const unsigned*)(h + ((size_t)eB.x << 7) + c0);
    unsigned hC = *(const unsigned*)(h + ((size_t)eC.x << 7) + c0);
    unsigned hD = *(const unsigned*)(h + ((size_t)eD.x << 7) + c0);
    unsigned hE = *(const unsigned*)(h + ((size_t)eE.x << 7) + c0);
    unsigned hF = *(const unsigned*)(h + ((size_t)eF.x << 7) + c0);
    unsigned hG = *(const unsigned*)(h + ((size_t)eG.x << 7) + c0);
    unsigned hH = *(const unsigned*)(h + ((size_t)eH.x << 7) + c0);
    float wA = __uint_as_float(head ? eA.z : eA.y);
    float wB = __uint_as_float(head ? eB.z : eB.y);
    float wC = __uint_as_float(head ? eC.z : eC.y);
    float wD = __uint_as_float(head ? eD.z : eD.y);
    float wE = __uint_as_float(head ? eE.z : eE.y);
    float wF = __uint_as_float(head ? eF.z : eF.y);
    float wG = __uint_as_float(head ? eG.z : eG.y);
    float wH = __uint_as_float(head ? eH.z : eH.y);
    den += ((wA + wB) + (wC + wD)) + ((wE + wF) + (wG + wH));
    acc0 = fmaf(wA, bflo(hA), acc0); acc1 = fmaf(wA, bfhi(hA), acc1);
    acc0 = fmaf(wB, bflo(hB), acc0); acc1 = fmaf(wB, bfhi(hB), acc1);
    acc0 = fmaf(wC, bflo(hC), acc0); acc1 = fmaf(wC, bfhi(hC), acc1);
    acc0 = fmaf(wD, bflo(hD), acc0); acc1 = fmaf(wD, bfhi(hD), acc1);
    acc0 = fmaf(wE, bflo(hE), acc0); acc1 = fmaf(wE, bfhi(hE), acc1);
    acc0 = fmaf(wF, bflo(hF), acc0); acc1 = fmaf(wF, bfhi(hF), acc1);
    acc0 = fmaf(wG, bflo(hG), acc0); acc1 = fmaf(wG, bfhi(hG), acc1);
    acc0 = fmaf(wH, bflo(hH), acc0); acc1 = fmaf(wH, bfhi(hH), acc1);
  }
  if (k + 3 < e0){
    int ku = __builtin_amdgcn_readfirstlane(k);
    uint4 eA = csr4[ku],     eB = csr4[ku + 1], eC = csr4[ku + 2], eD = csr4[ku + 3];
    unsigned hA = *(const unsigned*)(h + ((size_t)eA.x << 7) + c0);
    unsigned hB = *(const unsigned*)(h + ((size_t)eB.x << 7) + c0);
    unsigned hC = *(const unsigned*)(h + ((size_t)eC.x << 7) + c0);
    unsigned hD = *(const unsigned*)(h + ((size_t)eD.x << 7) + c0);
    float wA = __uint_as_float(head ? eA.z : eA.y);
    float wB = __uint_as_float(head ? eB.z : eB.y);
    float wC = __uint_as_float(head ? eC.z : eC.y);
    float wD = __uint_as_float(head ? eD.z : eD.y);
    den += (wA + wB) + (wC + wD);
    acc0 = fmaf(wA, bflo(hA), acc0); acc1 = fmaf(wA, bfhi(hA), acc1);
    acc0 = fmaf(wB, bflo(hB), acc0); acc1 = fmaf(wB, bfhi(hB), acc1);
    acc0 = fmaf(wC, bflo(hC), acc0); acc1 = fmaf(wC, bfhi(hC), acc1);
    acc0 = fmaf(wD, bflo(hD), acc0); acc1 = fmaf(wD, bfhi(hD), acc1);
    k += 4;
  }
  for (; k < e0; ++k){
    int ku = __builtin_amdgcn_readfirstlane(k);
    uint4 eA = csr4[ku];
    unsigned hA = *(const unsigned*)(h + ((size_t)eA.x << 7) + c0);
    float wA = __uint_as_float(head ? eA.z : eA.y);
    den += wA;
    acc0 = fmaf(wA, bflo(hA), acc0); acc1 = fmaf(wA, bfhi(hA), acc1);
  }

  float inv = 1.f / (den + 1e-16f);
  float o0 = elu_(acc0 * inv + b[c0]);
  float o1 = elu_(acc1 * inv + b[c0 + 1]);

  *(float2*)(&yly[wid][c0]) = make_float2(o0, o1);

  float s2 = fmaf(o0, vs2[c0], o1 * vs2[c0 + 1]);
  float d2 = fmaf(o0, vd2[c0], o1 * vd2[c0 + 1]);
  #pragma unroll
  for (int m = 32; m; m >>= 1){ s2 += __shfl_xor(s2, m); d2 += __shfl_xor(d2, m); }
  if (lane == 0){ as2[node] = s2; ad2[node] = d2; }

  asm volatile("s_waitcnt lgkmcnt(0)" ::: "memory");

  float zacc = 0.f;
  const float* yw = yly[wid];
  #pragma unroll 4
  for (int q = 0; q < 32; ++q){
    float4 yv = *(const float4*)(yw + 4 * q);
    const float* wr = W2 + (q * 4) * 64 + lane;
    zacc = fmaf(yv.x, wr[0],   zacc);
    zacc = fmaf(yv.y, wr[64],  zacc);
    zacc = fmaf(yv.z, wr[128], zacc);
    zacc = fmaf(yv.w, wr[192], zacc);
  }
  z[((unsigned)node << 6) + lane] = f2bf(zacc);
}

// ------- layer-2 agg: FULL-WAVE, 1 row/instr, scalar edge records (R11) -------
__global__ __launch_bounds__(256) void k_agg2(const int* __restrict__ off, const uint2* __restrict__ ew,
                                              const ushort* __restrict__ z,
                                              const float* __restrict__ b2, float* __restrict__ out){
  int node = blockIdx.x * 4 + (threadIdx.x >> 6);
  int lane = threadIdx.x & 63;
  int s0 = off[node], e0 = off[node + 1];

  float acc = 0.f, den = 0.f;
  int k = s0;
  for (; k + 7 < e0; k += 8){
    int ku = __builtin_amdgcn_readfirstlane(k);
    uint2 eA = ew[ku],     eB = ew[ku + 1], eC = ew[ku + 2], eD = ew[ku + 3];
    uint2 eE = ew[ku + 4], eF = ew[ku + 5], eG = ew[ku + 6], eH = ew[ku + 7];
    ushort zA = z[((size_t)eA.x << 6) + lane];
    ushort zB = z[((size_t)eB.x << 6) + lane];
    ushort zC = z[((size_t)eC.x << 6) + lane];
    ushort zD = z[((size_t)eD.x << 6) + lane];
    ushort zE = z[((size_t)eE.x << 6) + lane];
    ushort zF = z[((size_t)eF.x << 6) + lane];
    ushort zG = z[((size_t)eG.x << 6) + lane];
    ushort zH = z[((size_t)eH.x << 6) + lane];
    float wA = __uint_as_float(eA.y), wB = __uint_as_float(eB.y);
    float wC = __uint_as_float(eC.y), wD = __uint_as_float(eD.y);
    float wE = __uint_as_float(eE.y), wF = __uint_as_float(eF.y);
    float wG = __uint_as_float(eG.y), wH = __uint_as_float(eH.y);
    den += ((wA + wB) + (wC + wD)) + ((wE + wF) + (wG + wH));
    acc = fmaf(wA, bf2f(zA), acc); acc = fmaf(wB, bf2f(zB), acc);
    acc = fmaf(wC, bf2f(zC), acc); acc = fmaf(wD, bf2f(zD), acc);
    acc = fmaf(wE, bf2f(zE), acc); acc = fmaf(wF, bf2f(zF), acc);
    acc = fmaf(wG, bf2f(zG), acc); acc = fmaf(wH, bf2f(zH), acc);
  }
  if (k + 3 < e0){
    int ku = __builtin_amdgcn_readfirstlane(k);
    uint2 eA = ew[ku], eB = ew[ku + 1], eC = ew[ku + 2], eD = ew[ku + 3];
    ushort zA = z[((size_t)eA.x << 6) + lane];
    ushort zB = z[((size_t)eB.x << 6) + lane];
    ushort zC = z[((size_t)eC.x << 6) + lane];
    ushort zD = z[((size_t)eD.x << 6) + lane];
    float wA = __uint_as_float(eA.y), wB = __uint_as_float(eB.y);
    float wC = __uint_as_float(eC.y), wD = __uint_as_float(eD.y);
    den += (wA + wB) + (wC + wD);
    acc = fmaf(wA, bf2f(zA), acc); acc = fmaf(wB, bf2f(zB), acc);
    acc = fmaf(wC, bf2f(zC), acc); acc = fmaf(wD, bf2f(zD), acc);
    k += 4;
  }
  for (; k < e0; ++k){
    int ku = __builtin_amdgcn_readfirstlane(k);
    uint2 eA = ew[ku];
    ushort zA = z[((size_t)eA.x << 6) + lane];
    float wA = __uint_as_float(eA.y);
    den += wA;
    acc = fmaf(wA, bf2f(zA), acc);
  }

  float inv = 1.f / (den + 1e-16f);
  out[((unsigned)node << 6) + lane] = elu_(acc * inv + b2[lane]);
}

// ---------------- host ----------------
extern "C" void kernel_launch(void* const* d_in, const int* in_sizes, int n_in,
                              void* d_out, int out_size, void* d_ws, size_t ws_size,
                              hipStream_t stream){
  const float* x      = (const float*)d_in[0];
  const int*   ei     = (const int*)d_in[1];
  const float* W1     = (const float*)d_in[2];
  const float* a_src1 = (const float*)d_in[3];
  const float* a_dst1 = (const float*)d_in[4];
  const float* b1     = (const float*)d_in[5];
  const float* W2     = (const float*)d_in[6];
  const float* a_src2 = (const float*)d_in[7];
  const float* a_dst2 = (const float*)d_in[8];
  const float* b2     = (const float*)d_in[9];
  float* out = (float*)d_out;

  // workspace (~57 MB); h1 (bf16) lives in d_out until k_agg2 overwrites it
  char* ws = (char*)d_ws;
  size_t o = 0;
  auto alloc = [&](size_t bytes){ size_t r = o; o = (o + bytes + 255) & ~(size_t)255; return r; };
  int*    tmpN = (int*)(ws + alloc((size_t)N_NODES * 4));
  int*    bs   = (int*)(ws + alloc(512));
  int*    off  = (int*)(ws + alloc((size_t)(N_NODES + 1) * 4));
  uint4*  csr4 = (uint4*)(ws + alloc((size_t)TOT_E * 16));
  uint2*  ew   = (uint2*)(ws + alloc((size_t)TOT_E * 8));
  float*  as1  = (float*)(ws + alloc((size_t)N_NODES * 2 * 4));
  float*  ad1  = (float*)(ws + alloc((size_t)N_NODES * 2 * 4));
  float*  as2  = (float*)(ws + alloc((size_t)N_NODES * 4));
  float*  ad2  = (float*)(ws + alloc((size_t)N_NODES * 4));
  float*  vs2  = (float*)(ws + alloc(512));
  float*  vd2  = (float*)(ws + alloc(512));
  ushort* z    = (ushort*)(ws + alloc((size_t)N_NODES * 64 * 2));
  ushort* h1   = (ushort*)d_out;
  (void)ws_size; (void)in_sizes; (void)n_in; (void)out_size;

  const int nblk_edges = NBC;
  const int nblk_scan  = (N_NODES + 1023) / 1024;
  const int nblk_wave4 = N_NODES / 4;

  // zero counts first (count path of k_gc needs it)
  hipMemsetAsync(tmpN, 0, (size_t)N_NODES * 4, stream);

  // fused: gemm1 (+alpha1) | count | prep2 — count is independent of gemm
  k_gc<<<NBG + NBC + 1, 256, 0, stream>>>(x, W1, a_src1, a_dst1, h1, as1, ad1,
                                          ei, tmpN, W2, a_src2, a_dst2, vs2, vd2, N_NODES);

  // scans + fill (packed records with fused layer-1 edge weights)
  k_scan1 <<<nblk_scan, 1024, 0, stream>>>(tmpN, off, bs);
  k_scan2 <<<1, 128, 0, stream>>>(bs, off, nblk_scan);
  k_scan3 <<<nblk_scan, 1024, 0, stream>>>(off, tmpN, bs);
  k_fill_w<<<nblk_edges, 256, 0, stream>>>(ei, tmpN, csr4, as1, ad1);

  // layer-1 agg: full-wave rows, scalar edge records, fused z=y@W2 + alpha2
  k_agg1 <<<nblk_wave4, 256, 0, stream>>>(off, csr4, h1, b1, vs2, vd2, W2, z, as2, ad2);

  // layer-2 packed edge weights, then full-wave agg2
  k_ew2  <<<nblk_edges, 256, 0, stream>>>(csr4, as2, ad2, ew);
  k_agg2 <<<nblk_wave4, 256, 0, stream>>>(off, ew, z, b2, out);
}